// Round 14
// baseline (145.071 us; speedup 1.0000x reference)
//
#include <hip/hip_runtime.h>
#include <hip/hip_bf16.h>

typedef _Float16 f16;
typedef _Float16 f16x8 __attribute__((ext_vector_type(8)));
typedef _Float16 f16x4 __attribute__((ext_vector_type(4)));
typedef float f32x4 __attribute__((ext_vector_type(4)));

#define QPAD 136   // 128 + 8 f16 -> 272B rows, 16B aligned
#define PADK2 72   // 64 + 8 f16

#define W1SCALE 262144.0f              // 2^18: lifts W1 (~2e-6, f16-denormal!) to ~0.5
#define W1DESCALE 3.814697265625e-06f  // 2^-18, applied in f32 epilogue of k_dft_inv

static __device__ __forceinline__ f32x4 mfma16(f16x8 a, f16x8 b, f32x4 c) {
  return __builtin_amdgcn_mfma_f32_16x16x32_f16(a, b, c, 0, 0, 0);
}

// ---------------- S0: tables + weight casts, one launch ----------------
__global__ __launch_bounds__(256) void k_prep(f16* __restrict__ FhT, f16* __restrict__ Gh,
                                              const float* __restrict__ Wq,
                                              const float* __restrict__ Wo,
                                              f16* __restrict__ Wq16,
                                              f16* __restrict__ Wo16) {
  int idx = blockIdx.x * 256 + threadIdx.x;  // 0..131071
  const float w = 6.28318530717958647692f / 2048.0f;
  {
    int k2 = idx >> 11, l = idx & 2047;
    int k = k2 & 31;
    float th = (float)((k * l) & 2047) * w;
    float v = (k2 < 32) ? cosf(th) : -sinf(th);
    FhT[k2 * 2048 + l] = (f16)v;
  }
  {
    int l = idx >> 6, kk = idx & 63;
    int k = kk & 31;
    float th = (float)((k * l) & 2047) * w;
    float v;
    if (kk < 32) v = ((k == 0) ? 1.0f : 2.0f) * (1.0f / 2048.0f) * cosf(th);
    else         v = (k == 0) ? 0.0f : (-2.0f / 2048.0f) * sinf(th);
    Gh[l * 64 + kk] = (f16)v;
  }
  {
    const float* src = (idx < 65536) ? Wq : Wo;
    f16* dst = (idx < 65536) ? Wq16 : Wo16;
    int i = idx & 65535;
    float4 v = ((const float4*)src)[i];
    f16x4 o = {(f16)v.x, (f16)v.y, (f16)v.z, (f16)v.w};
    *(f16x4*)(dst + (size_t)i * 4) = o;
  }
}

// ---------------- S1: split-K forward DFT, BK=128, float4 query loads + prefetch ----------------
__global__ __launch_bounds__(256) void k_dft_fwd(const f16* __restrict__ FhT,
                                                 const float* __restrict__ queries,
                                                 f16* __restrict__ p16) {
  __shared__ __align__(16) f16 As[64 * QPAD];  // [k2][l]
  __shared__ __align__(16) f16 Bs[64 * QPAD];  // [j][l]
  const int n0 = blockIdx.x * 64;
  const int b  = blockIdx.y;
  const int kb = blockIdx.z * 512;
  const int t = threadIdx.x;
  const int wid = t >> 6, lane = t & 63;
  const int mh = wid & 1, nh = wid >> 1;
  const int l15 = lane & 15, kq = lane >> 4;
  const int arow = t >> 2, ac0 = (t & 3) << 5;       // A: row, 32-col chunk
  const int fc = (t & 15) << 2, q8 = (t >> 4) << 3;  // B: 4-col group, 8-row group

  float4 qv4[8];  // prefetched queries: 8 rows x 4 cols
  f16x8 av[4];    // prefetched FhT row chunk

  auto issue = [&](int ph) {
    const int k0 = kb + ph * 128;
    const float* qp = queries + ((size_t)b * 2048 + k0 + q8) * 512 + n0 + fc;
#pragma unroll
    for (int r = 0; r < 8; ++r) qv4[r] = *(const float4*)(qp + (size_t)r * 512);
#pragma unroll
    for (int j = 0; j < 4; ++j)
      av[j] = *(const f16x8*)(FhT + (size_t)arow * 2048 + k0 + ac0 + j * 8);
  };

  issue(0);
  f32x4 acc[2][2] = {};
  for (int ph = 0; ph < 4; ++ph) {
    __syncthreads();
#pragma unroll
    for (int j = 0; j < 4; ++j)
      *(f16x8*)(As + arow * QPAD + ac0 + j * 8) = av[j];
#pragma unroll
    for (int c = 0; c < 4; ++c) {
      const float* f0 = (const float*)&qv4[0];
      const float* f1 = (const float*)&qv4[1];
      const float* f2 = (const float*)&qv4[2];
      const float* f3 = (const float*)&qv4[3];
      const float* f4 = (const float*)&qv4[4];
      const float* f5 = (const float*)&qv4[5];
      const float* f6 = (const float*)&qv4[6];
      const float* f7 = (const float*)&qv4[7];
      f16x8 pk = {(f16)f0[c], (f16)f1[c], (f16)f2[c], (f16)f3[c],
                  (f16)f4[c], (f16)f5[c], (f16)f6[c], (f16)f7[c]};
      *(f16x8*)(Bs + (fc + c) * QPAD + q8) = pk;
    }
    __syncthreads();
    if (ph < 3) issue(ph + 1);
#pragma unroll
    for (int ks = 0; ks < 4; ++ks) {
      const int kofs = ks * 32 + kq * 8;
      f16x8 a0 = *(const f16x8*)(As + (mh * 32 + 0  + l15) * QPAD + kofs);
      f16x8 a1 = *(const f16x8*)(As + (mh * 32 + 16 + l15) * QPAD + kofs);
      f16x8 b0 = *(const f16x8*)(Bs + (nh * 32 + 0  + l15) * QPAD + kofs);
      f16x8 b1 = *(const f16x8*)(Bs + (nh * 32 + 16 + l15) * QPAD + kofs);
      acc[0][0] = mfma16(a0, b0, acc[0][0]);
      acc[0][1] = mfma16(a0, b1, acc[0][1]);
      acc[1][0] = mfma16(a1, b0, acc[1][0]);
      acc[1][1] = mfma16(a1, b1, acc[1][1]);
    }
  }
#pragma unroll
  for (int mf = 0; mf < 2; ++mf)
#pragma unroll
    for (int nf = 0; nf < 2; ++nf)
#pragma unroll
      for (int r = 0; r < 4; ++r) {
        int k2 = mh * 32 + mf * 16 + kq * 4 + r;
        int col = n0 + nh * 32 + nf * 16 + l15;
        p16[((size_t)blockIdx.z * 2048 + b * 64 + k2) * 512 + col] = (f16)acc[mf][nf][r];
      }
}

// ------- S2/S4: C = (sum_NP planes of P) @ Bnk^T, 64M x 32N tile, 8 waves/block -------
template <int NP>
__global__ __launch_bounds__(512) void k_gemm_red(const f16* __restrict__ P,
                                                  const f16* __restrict__ Bnk,
                                                  f16* __restrict__ C,
                                                  const float* __restrict__ bias0,
                                                  float bscale, int selt) {
  __shared__ __align__(16) f16 As[64 * QPAD];
  __shared__ __align__(16) f16 Bs[32 * QPAD];
  const int n0 = blockIdx.x * 32, m0 = blockIdx.y * 64;
  const int t = threadIdx.x;
  const int wv = t >> 6, lane = t & 63;
  const int mh = wv & 3, nh = wv >> 2;
  const int l15 = lane & 15, kq = lane >> 4;
  const int arow = t >> 3, ac0 = (t & 7) << 4;   // A: 64 rows x 8 chunks of 16
  const int brow = t >> 4, bc0 = (t & 15) << 3;  // B: 32 rows x 16 chunks of 8
  f32x4 acc = {};
  for (int ph = 0; ph < 4; ++ph) {
    const int k0 = ph * 128;
    __syncthreads();
    f16x8 v[2][NP];
    const size_t aidx = (size_t)(m0 + arow) * 512 + k0 + ac0;
#pragma unroll
    for (int h = 0; h < 2; ++h)
#pragma unroll
      for (int c = 0; c < NP; ++c)
        v[h][c] = *(const f16x8*)(P + (size_t)c * 1048576 + aidx + h * 8);
    f16x8 bv = *(const f16x8*)(Bnk + (size_t)(n0 + brow) * 512 + k0 + bc0);
#pragma unroll
    for (int h = 0; h < 2; ++h) {
      f16x8 s = v[h][0];
#pragma unroll
      for (int c = 1; c < NP; ++c) s = s + v[h][c];
      *(f16x8*)(As + arow * QPAD + ac0 + h * 8) = s;
    }
    *(f16x8*)(Bs + brow * QPAD + bc0) = bv;
    __syncthreads();
#pragma unroll
    for (int ks = 0; ks < 4; ++ks) {
      const int kofs = ks * 32 + kq * 8;
      f16x8 a = *(const f16x8*)(As + (mh * 16 + l15) * QPAD + kofs);
      f16x8 b = *(const f16x8*)(Bs + (nh * 16 + l15) * QPAD + kofs);
      acc = mfma16(a, b, acc);
    }
  }
#pragma unroll
  for (int r = 0; r < 4; ++r) {
    int mg = m0 + mh * 16 + kq * 4 + r;
    int col = n0 + nh * 16 + l15;
    float cv = acc[r];
    if (bias0 != nullptr && (mg & 63) == 0) cv += bscale * bias0[col];
    size_t didx = selt ? (((size_t)(mg & 63) * 32 + (mg >> 6)) * 512 + col)
                       : ((size_t)mg * 512 + col);
    C[didx] = (f16)cv;
  }
}

// ---------------- S3: fused W1-transpose + per-mode complex mix, i-split 4 ----------------
__global__ __launch_bounds__(512) void k_modes_fused(const float* __restrict__ W1r,
                                                     const float* __restrict__ W1i,
                                                     const f16* __restrict__ selT,
                                                     f16* __restrict__ pmode) {
  __shared__ __align__(16) f16 Wst[2][16][648];
  const int o0 = blockIdx.x * 16, m0 = blockIdx.y * 16, is = blockIdx.z;
  const int t = threadIdx.x;
  const int lane = t & 63, wv = t >> 6;
  const int l15 = lane & 15, kq = lane >> 4, kofs = kq << 3;
  const int mq = t & 3, p = t >> 2;
  const int soo = p & 15, sib = p >> 4;
  f32x4 accR[2][2] = {}, accI[2][2] = {};
  const int ibase = is * 128;
  for (int ch = 0; ch < 4; ++ch) {
    const int i0c = ibase + ch * 32;
    __syncthreads();
#pragma unroll
    for (int ri = 0; ri < 2; ++ri) {
      const float* src = ri ? W1i : W1r;
#pragma unroll
      for (int qq = 0; qq < 4; ++qq) {
        int ii = sib + 8 * qq;
        const float4 v = *(const float4*)(src + (size_t)(i0c + ii) * 16384 +
                                          (o0 + soo) * 32 + m0 + mq * 4);
        f16* wp = &Wst[ri][mq * 4][soo * 40 + ii];
        wp[0 * 648] = (f16)(W1SCALE * v.x);
        wp[1 * 648] = (f16)(W1SCALE * v.y);
        wp[2 * 648] = (f16)(W1SCALE * v.z);
        wp[3 * 648] = (f16)(W1SCALE * v.w);
      }
    }
    __syncthreads();
#pragma unroll
    for (int ml = 0; ml < 2; ++ml) {
      const int mloc = 2 * wv + ml;
      const int mg = m0 + mloc;
      f16x8 ar0 = *(const f16x8*)(selT + ((size_t)mg * 32 + 0  + l15) * 512 + i0c + kofs);
      f16x8 ar1 = *(const f16x8*)(selT + ((size_t)mg * 32 + 16 + l15) * 512 + i0c + kofs);
      f16x8 ai0 = *(const f16x8*)(selT + ((size_t)(32 + mg) * 32 + 0  + l15) * 512 + i0c + kofs);
      f16x8 ai1 = *(const f16x8*)(selT + ((size_t)(32 + mg) * 32 + 16 + l15) * 512 + i0c + kofs);
      f16x8 br = *(const f16x8*)(&Wst[0][mloc][l15 * 40 + kofs]);
      f16x8 bi = *(const f16x8*)(&Wst[1][mloc][l15 * 40 + kofs]);
      f16x8 ain0 = -ai0, ain1 = -ai1;
      accR[ml][0] = mfma16(ar0,  br, accR[ml][0]);
      accR[ml][0] = mfma16(ain0, bi, accR[ml][0]);
      accI[ml][0] = mfma16(ar0,  bi, accI[ml][0]);
      accI[ml][0] = mfma16(ai0,  br, accI[ml][0]);
      accR[ml][1] = mfma16(ar1,  br, accR[ml][1]);
      accR[ml][1] = mfma16(ain1, bi, accR[ml][1]);
      accI[ml][1] = mfma16(ar1,  bi, accI[ml][1]);
      accI[ml][1] = mfma16(ai1,  br, accI[ml][1]);
    }
  }
#pragma unroll
  for (int ml = 0; ml < 2; ++ml) {
    const int mg = m0 + 2 * wv + ml;
#pragma unroll
    for (int bt = 0; bt < 2; ++bt)
#pragma unroll
      for (int r = 0; r < 4; ++r) {
        int bb = bt * 16 + kq * 4 + r;
        int og = o0 + l15;
        pmode[((size_t)is * 2048 + bb * 64 + mg) * 512 + og]      = (f16)accR[ml][bt][r];
        pmode[((size_t)is * 2048 + bb * 64 + 32 + mg) * 512 + og] = (f16)accI[ml][bt][r];
      }
  }
}

// ---------------- S5: out = (Gh @ u) * 2^-18 + bo, LDS-staged float4 output ----------------
// Epilogue: f32 tile staged in LDS (aliasing As/Bs after barrier), then fully
// coalesced float4 stores (1KB/wave-instr) instead of 16 scalar dword stores.
__global__ __launch_bounds__(256) void k_dft_inv(const f16* __restrict__ Gh,
                                                 const f16* __restrict__ u,
                                                 const float* __restrict__ bo,
                                                 float* __restrict__ out) {
  __shared__ __align__(16) f16 S[2 * 64 * PADK2];  // As | Bs, reused as Co f32[64][68]
  f16* As = S;
  f16* Bs = S + 64 * PADK2;
  float* Co = (float*)S;                            // 64*68*4 = 17408B <= 18432B
  const int n0 = blockIdx.x * 64, l0 = blockIdx.y * 64, b = blockIdx.z;
  const int t = threadIdx.x, wid = t >> 6, lane = t & 63;
  const int mh = wid & 1, nh = wid >> 1;
#pragma unroll
  for (int p = 0; p < 2; ++p) {
    int v = t + 256 * p, row = v >> 3, c8 = (v & 7) << 3;
    *(f16x8*)(As + row * PADK2 + c8) = *(const f16x8*)(Gh + (size_t)(l0 + row) * 64 + c8);
  }
  {
    int col = t & 63, kg = t >> 6;
    const f16* up = u + ((size_t)b * 64 + kg * 16) * 512 + n0 + col;
    f16 vv[16];
#pragma unroll
    for (int s = 0; s < 16; ++s) vv[s] = up[(size_t)s * 512];
#pragma unroll
    for (int s4 = 0; s4 < 4; ++s4) {
      f16x4 pk = {vv[s4 * 4], vv[s4 * 4 + 1], vv[s4 * 4 + 2], vv[s4 * 4 + 3]};
      *(f16x4*)(Bs + col * PADK2 + kg * 16 + s4 * 4) = pk;
    }
  }
  __syncthreads();
  f32x4 acc[2][2] = {};
#pragma unroll
  for (int ks = 0; ks < 2; ++ks) {
    const int kofs = ks * 32 + ((lane >> 4) << 3);
    f16x8 a0 = *(const f16x8*)(As + (mh * 32 + 0  + (lane & 15)) * PADK2 + kofs);
    f16x8 a1 = *(const f16x8*)(As + (mh * 32 + 16 + (lane & 15)) * PADK2 + kofs);
    f16x8 b0 = *(const f16x8*)(Bs + (nh * 32 + 0  + (lane & 15)) * PADK2 + kofs);
    f16x8 b1 = *(const f16x8*)(Bs + (nh * 32 + 16 + (lane & 15)) * PADK2 + kofs);
    acc[0][0] = mfma16(a0, b0, acc[0][0]);
    acc[0][1] = mfma16(a0, b1, acc[0][1]);
    acc[1][0] = mfma16(a1, b0, acc[1][0]);
    acc[1][1] = mfma16(a1, b1, acc[1][1]);
  }
  __syncthreads();  // all MFMA reads of As/Bs done; safe to alias as Co
#pragma unroll
  for (int mf = 0; mf < 2; ++mf)
#pragma unroll
    for (int nf = 0; nf < 2; ++nf)
#pragma unroll
      for (int r = 0; r < 4; ++r) {
        int ll = mh * 32 + mf * 16 + ((lane >> 4) << 2) + r;          // 0..63
        int cc = nh * 32 + nf * 16 + (lane & 15);                     // 0..63
        Co[ll * 68 + cc] = acc[mf][nf][r] * W1DESCALE + bo[n0 + cc];  // same op order
      }
  __syncthreads();
  {
    const int row = t >> 2, c16 = (t & 3) << 4;
    float* op = out + ((size_t)b * 2048 + l0 + row) * 512 + n0 + c16;
    const float* cp = Co + row * 68 + c16;
#pragma unroll
    for (int j = 0; j < 4; ++j)
      *(float4*)(op + j * 4) = *(const float4*)(cp + j * 4);
  }
}

extern "C" void kernel_launch(void* const* d_in, const int* in_sizes, int n_in,
                              void* d_out, int out_size, void* d_ws, size_t ws_size,
                              hipStream_t stream) {
  const float* queries = (const float*)d_in[0];
  const float* Wq      = (const float*)d_in[1];
  const float* bq      = (const float*)d_in[2];
  const float* W1r     = (const float*)d_in[3];
  const float* W1i     = (const float*)d_in[4];
  const float* Wo      = (const float*)d_in[5];
  const float* bo      = (const float*)d_in[6];
  float* out           = (float*)d_out;

  char* ws = (char*)d_ws;
  size_t off = 0;
  auto alloc = [&](size_t bytes) {
    off = (off + 255) & ~(size_t)255;
    char* p = ws + off;
    off += bytes;
    return p;
  };
  f16* FhT    = (f16*)alloc((size_t)64 * 2048 * 2);
  f16* Gh     = (f16*)alloc((size_t)2048 * 64 * 2);
  f16* Wq16   = (f16*)alloc((size_t)512 * 512 * 2);
  f16* Wo16   = (f16*)alloc((size_t)512 * 512 * 2);
  f16* p16    = (f16*)alloc((size_t)4 * 2048 * 512 * 2);  // dft split-K f16 partials
  f16* selT   = (f16*)alloc((size_t)2048 * 512 * 2);      // [k2 plane][b][i]
  f16* pmode  = (f16*)alloc((size_t)4 * 2048 * 512 * 2);  // modes split f16 partials
  f16* u16    = (f16*)alloc((size_t)2048 * 512 * 2);

  hipLaunchKernelGGL(k_prep, dim3(512), dim3(256), 0, stream, FhT, Gh, Wq, Wo, Wq16, Wo16);
  hipLaunchKernelGGL(k_dft_fwd, dim3(8, 32, 4), dim3(256), 0, stream, FhT, queries, p16);
  hipLaunchKernelGGL(k_gemm_red<4>, dim3(16, 32), dim3(512), 0, stream, p16, Wq16, selT,
                     bq, 2048.0f, 1);
  hipLaunchKernelGGL(k_modes_fused, dim3(32, 2, 4), dim3(512), 0, stream,
                     W1r, W1i, selT, pmode);
  hipLaunchKernelGGL(k_gemm_red<4>, dim3(16, 32), dim3(512), 0, stream, pmode, Wo16, u16,
                     (const float*)nullptr, 0.0f, 0);
  hipLaunchKernelGGL(k_dft_inv, dim3(8, 32, 32), dim3(256), 0, stream, Gh, u16, bo, out);
}

// Round 15
// 123.256 us; speedup vs baseline: 1.1770x; 1.1770x over previous
//
#include <hip/hip_runtime.h>
#include <hip/hip_bf16.h>

typedef _Float16 f16;
typedef _Float16 f16x8 __attribute__((ext_vector_type(8)));
typedef _Float16 f16x4 __attribute__((ext_vector_type(4)));
typedef float f32x4 __attribute__((ext_vector_type(4)));

#define QPAD 136   // 128 + 8 f16 -> 272B rows, 16B aligned
#define PADK2 72   // 64 + 8 f16

#define W1SCALE 262144.0f              // 2^18: lifts W1 (~2e-6, f16-denormal!) to ~0.5
#define W1DESCALE 3.814697265625e-06f  // 2^-18, applied in f32 epilogue of k_dft_inv

static __device__ __forceinline__ f32x4 mfma16(f16x8 a, f16x8 b, f32x4 c) {
  return __builtin_amdgcn_mfma_f32_16x16x32_f16(a, b, c, 0, 0, 0);
}

// ---------------- S0: tables + weight casts, one launch ----------------
__global__ __launch_bounds__(256) void k_prep(f16* __restrict__ FhT, f16* __restrict__ Gh,
                                              const float* __restrict__ Wq,
                                              const float* __restrict__ Wo,
                                              f16* __restrict__ Wq16,
                                              f16* __restrict__ Wo16) {
  int idx = blockIdx.x * 256 + threadIdx.x;  // 0..131071
  const float w = 6.28318530717958647692f / 2048.0f;
  {
    int k2 = idx >> 11, l = idx & 2047;
    int k = k2 & 31;
    float th = (float)((k * l) & 2047) * w;
    float v = (k2 < 32) ? cosf(th) : -sinf(th);
    FhT[k2 * 2048 + l] = (f16)v;
  }
  {
    int l = idx >> 6, kk = idx & 63;
    int k = kk & 31;
    float th = (float)((k * l) & 2047) * w;
    float v;
    if (kk < 32) v = ((k == 0) ? 1.0f : 2.0f) * (1.0f / 2048.0f) * cosf(th);
    else         v = (k == 0) ? 0.0f : (-2.0f / 2048.0f) * sinf(th);
    Gh[l * 64 + kk] = (f16)v;
  }
  {
    const float* src = (idx < 65536) ? Wq : Wo;
    f16* dst = (idx < 65536) ? Wq16 : Wo16;
    int i = idx & 65535;
    float4 v = ((const float4*)src)[i];
    f16x4 o = {(f16)v.x, (f16)v.y, (f16)v.z, (f16)v.w};
    *(f16x4*)(dst + (size_t)i * 4) = o;
  }
}

// ---------------- S1: split-K forward DFT, BK=128, register-prefetch pipeline ----------------
// p16[c][b*64+k2][col] = sum_{l in 512-chunk c} FhT[k2,l] * queries[b,l,col]
__global__ __launch_bounds__(256) void k_dft_fwd(const f16* __restrict__ FhT,
                                                 const float* __restrict__ queries,
                                                 f16* __restrict__ p16) {
  __shared__ __align__(16) f16 As[64 * QPAD];  // [k2][l]
  __shared__ __align__(16) f16 Bs[64 * QPAD];  // [j][l]
  const int n0 = blockIdx.x * 64;
  const int b  = blockIdx.y;
  const int kb = blockIdx.z * 512;
  const int t = threadIdx.x;
  const int wid = t >> 6, lane = t & 63;
  const int mh = wid & 1, nh = wid >> 1;
  const int l15 = lane & 15, kq = lane >> 4;
  const int arow = t >> 2, ac0 = (t & 3) << 5;   // A: row, 32-col chunk
  const int bcol = t & 63, bkg = t >> 6;          // B: col, 32-row group

  float qv[32];   // prefetched queries (one phase)
  f16x8 av[4];    // prefetched FhT row chunk

  auto issue = [&](int ph) {
    const int k0 = kb + ph * 128;
    const float* qp = queries + ((size_t)b * 2048 + k0 + bkg * 32) * 512 + n0 + bcol;
#pragma unroll
    for (int r = 0; r < 32; ++r) qv[r] = qp[(size_t)r * 512];
#pragma unroll
    for (int j = 0; j < 4; ++j)
      av[j] = *(const f16x8*)(FhT + (size_t)arow * 2048 + k0 + ac0 + j * 8);
  };

  issue(0);
  f32x4 acc[2][2] = {};
  for (int ph = 0; ph < 4; ++ph) {
    __syncthreads();
#pragma unroll
    for (int j = 0; j < 4; ++j)
      *(f16x8*)(As + arow * QPAD + ac0 + j * 8) = av[j];
#pragma unroll
    for (int s = 0; s < 4; ++s) {
      f16x8 pk = {(f16)qv[s*8+0], (f16)qv[s*8+1], (f16)qv[s*8+2], (f16)qv[s*8+3],
                  (f16)qv[s*8+4], (f16)qv[s*8+5], (f16)qv[s*8+6], (f16)qv[s*8+7]};
      *(f16x8*)(Bs + bcol * QPAD + bkg * 32 + s * 8) = pk;
    }
    __syncthreads();
    if (ph < 3) issue(ph + 1);
#pragma unroll
    for (int ks = 0; ks < 4; ++ks) {
      const int kofs = ks * 32 + kq * 8;
      f16x8 a0 = *(const f16x8*)(As + (mh * 32 + 0  + l15) * QPAD + kofs);
      f16x8 a1 = *(const f16x8*)(As + (mh * 32 + 16 + l15) * QPAD + kofs);
      f16x8 b0 = *(const f16x8*)(Bs + (nh * 32 + 0  + l15) * QPAD + kofs);
      f16x8 b1 = *(const f16x8*)(Bs + (nh * 32 + 16 + l15) * QPAD + kofs);
      acc[0][0] = mfma16(a0, b0, acc[0][0]);
      acc[0][1] = mfma16(a0, b1, acc[0][1]);
      acc[1][0] = mfma16(a1, b0, acc[1][0]);
      acc[1][1] = mfma16(a1, b1, acc[1][1]);
    }
  }
#pragma unroll
  for (int mf = 0; mf < 2; ++mf)
#pragma unroll
    for (int nf = 0; nf < 2; ++nf)
#pragma unroll
      for (int r = 0; r < 4; ++r) {
        int k2 = mh * 32 + mf * 16 + kq * 4 + r;
        int col = n0 + nh * 32 + nf * 16 + l15;
        p16[((size_t)blockIdx.z * 2048 + b * 64 + k2) * 512 + col] = (f16)acc[mf][nf][r];
      }
}

// ------- S2/S4: C = (sum_NP planes of P) @ Bnk^T, 64M x 32N tile, 8 waves/block -------
// selt=1: write C to selT[k2][b][col] planes (k2=mg&63, b=mg>>6); else C[mg][col].
template <int NP>
__global__ __launch_bounds__(512) void k_gemm_red(const f16* __restrict__ P,
                                                  const f16* __restrict__ Bnk,
                                                  f16* __restrict__ C,
                                                  const float* __restrict__ bias0,
                                                  float bscale, int selt) {
  __shared__ __align__(16) f16 As[64 * QPAD];
  __shared__ __align__(16) f16 Bs[32 * QPAD];
  const int n0 = blockIdx.x * 32, m0 = blockIdx.y * 64;
  const int t = threadIdx.x;
  const int wv = t >> 6, lane = t & 63;
  const int mh = wv & 3, nh = wv >> 2;
  const int l15 = lane & 15, kq = lane >> 4;
  const int arow = t >> 3, ac0 = (t & 7) << 4;   // A: 64 rows x 8 chunks of 16
  const int brow = t >> 4, bc0 = (t & 15) << 3;  // B: 32 rows x 16 chunks of 8
  f32x4 acc = {};
  for (int ph = 0; ph < 4; ++ph) {
    const int k0 = ph * 128;
    __syncthreads();
    f16x8 v[2][NP];
    const size_t aidx = (size_t)(m0 + arow) * 512 + k0 + ac0;
#pragma unroll
    for (int h = 0; h < 2; ++h)
#pragma unroll
      for (int c = 0; c < NP; ++c)
        v[h][c] = *(const f16x8*)(P + (size_t)c * 1048576 + aidx + h * 8);
    f16x8 bv = *(const f16x8*)(Bnk + (size_t)(n0 + brow) * 512 + k0 + bc0);
#pragma unroll
    for (int h = 0; h < 2; ++h) {
      f16x8 s = v[h][0];
#pragma unroll
      for (int c = 1; c < NP; ++c) s = s + v[h][c];
      *(f16x8*)(As + arow * QPAD + ac0 + h * 8) = s;
    }
    *(f16x8*)(Bs + brow * QPAD + bc0) = bv;
    __syncthreads();
#pragma unroll
    for (int ks = 0; ks < 4; ++ks) {
      const int kofs = ks * 32 + kq * 8;
      f16x8 a = *(const f16x8*)(As + (mh * 16 + l15) * QPAD + kofs);
      f16x8 b = *(const f16x8*)(Bs + (nh * 16 + l15) * QPAD + kofs);
      acc = mfma16(a, b, acc);
    }
  }
#pragma unroll
  for (int r = 0; r < 4; ++r) {
    int mg = m0 + mh * 16 + kq * 4 + r;
    int col = n0 + nh * 16 + l15;
    float cv = acc[r];
    if (bias0 != nullptr && (mg & 63) == 0) cv += bscale * bias0[col];
    size_t didx = selt ? (((size_t)(mg & 63) * 32 + (mg >> 6)) * 512 + col)
                       : ((size_t)mg * 512 + col);
    C[didx] = (f16)cv;
  }
}

// ---------------- S3: fused W1-transpose + per-mode complex mix, i-split 4 ----------------
// pmode[is][b*64 + (RI?32:0)+m][o] = sum_{i in 128-split} selT ∘ W1[i][o][m]
__global__ __launch_bounds__(512) void k_modes_fused(const float* __restrict__ W1r,
                                                     const float* __restrict__ W1i,
                                                     const f16* __restrict__ selT,
                                                     f16* __restrict__ pmode) {
  __shared__ __align__(16) f16 Wst[2][16][648];
  const int o0 = blockIdx.x * 16, m0 = blockIdx.y * 16, is = blockIdx.z;
  const int t = threadIdx.x;
  const int lane = t & 63, wv = t >> 6;
  const int l15 = lane & 15, kq = lane >> 4, kofs = kq << 3;
  const int mq = t & 3, p = t >> 2;
  const int soo = p & 15, sib = p >> 4;
  f32x4 accR[2][2] = {}, accI[2][2] = {};
  const int ibase = is * 128;
  for (int ch = 0; ch < 4; ++ch) {
    const int i0c = ibase + ch * 32;
    __syncthreads();
#pragma unroll
    for (int ri = 0; ri < 2; ++ri) {
      const float* src = ri ? W1i : W1r;
#pragma unroll
      for (int qq = 0; qq < 4; ++qq) {
        int ii = sib + 8 * qq;
        const float4 v = *(const float4*)(src + (size_t)(i0c + ii) * 16384 +
                                          (o0 + soo) * 32 + m0 + mq * 4);
        f16* wp = &Wst[ri][mq * 4][soo * 40 + ii];
        wp[0 * 648] = (f16)(W1SCALE * v.x);
        wp[1 * 648] = (f16)(W1SCALE * v.y);
        wp[2 * 648] = (f16)(W1SCALE * v.z);
        wp[3 * 648] = (f16)(W1SCALE * v.w);
      }
    }
    __syncthreads();
#pragma unroll
    for (int ml = 0; ml < 2; ++ml) {
      const int mloc = 2 * wv + ml;
      const int mg = m0 + mloc;
      f16x8 ar0 = *(const f16x8*)(selT + ((size_t)mg * 32 + 0  + l15) * 512 + i0c + kofs);
      f16x8 ar1 = *(const f16x8*)(selT + ((size_t)mg * 32 + 16 + l15) * 512 + i0c + kofs);
      f16x8 ai0 = *(const f16x8*)(selT + ((size_t)(32 + mg) * 32 + 0  + l15) * 512 + i0c + kofs);
      f16x8 ai1 = *(const f16x8*)(selT + ((size_t)(32 + mg) * 32 + 16 + l15) * 512 + i0c + kofs);
      f16x8 br = *(const f16x8*)(&Wst[0][mloc][l15 * 40 + kofs]);
      f16x8 bi = *(const f16x8*)(&Wst[1][mloc][l15 * 40 + kofs]);
      f16x8 ain0 = -ai0, ain1 = -ai1;
      accR[ml][0] = mfma16(ar0,  br, accR[ml][0]);
      accR[ml][0] = mfma16(ain0, bi, accR[ml][0]);
      accI[ml][0] = mfma16(ar0,  bi, accI[ml][0]);
      accI[ml][0] = mfma16(ai0,  br, accI[ml][0]);
      accR[ml][1] = mfma16(ar1,  br, accR[ml][1]);
      accR[ml][1] = mfma16(ain1, bi, accR[ml][1]);
      accI[ml][1] = mfma16(ar1,  bi, accI[ml][1]);
      accI[ml][1] = mfma16(ai1,  br, accI[ml][1]);
    }
  }
#pragma unroll
  for (int ml = 0; ml < 2; ++ml) {
    const int mg = m0 + 2 * wv + ml;
#pragma unroll
    for (int bt = 0; bt < 2; ++bt)
#pragma unroll
      for (int r = 0; r < 4; ++r) {
        int bb = bt * 16 + kq * 4 + r;
        int og = o0 + l15;
        pmode[((size_t)is * 2048 + bb * 64 + mg) * 512 + og]      = (f16)accR[ml][bt][r];
        pmode[((size_t)is * 2048 + bb * 64 + 32 + mg) * 512 + og] = (f16)accI[ml][bt][r];
      }
  }
}

// ---------------- S5: out[b,l,o] = (sum_k2 Gh[l,k2]*u[b,k2,o]) * 2^-18 + bo[o] ----------------
__global__ __launch_bounds__(256) void k_dft_inv(const f16* __restrict__ Gh,
                                                 const f16* __restrict__ u,
                                                 const float* __restrict__ bo,
                                                 float* __restrict__ out) {
  __shared__ __align__(16) f16 As[64 * PADK2];  // [l][k2]
  __shared__ __align__(16) f16 Bs[64 * PADK2];  // [o][k2]
  const int n0 = blockIdx.x * 64, l0 = blockIdx.y * 64, b = blockIdx.z;
  const int t = threadIdx.x, wid = t >> 6, lane = t & 63;
  const int mh = wid & 1, nh = wid >> 1;
#pragma unroll
  for (int p = 0; p < 2; ++p) {
    int v = t + 256 * p, row = v >> 3, c8 = (v & 7) << 3;
    *(f16x8*)(As + row * PADK2 + c8) = *(const f16x8*)(Gh + (size_t)(l0 + row) * 64 + c8);
  }
  {
    int col = t & 63, kg = t >> 6;
    const f16* up = u + ((size_t)b * 64 + kg * 16) * 512 + n0 + col;
    f16 vv[16];
#pragma unroll
    for (int s = 0; s < 16; ++s) vv[s] = up[(size_t)s * 512];
#pragma unroll
    for (int s4 = 0; s4 < 4; ++s4) {
      f16x4 pk = {vv[s4 * 4], vv[s4 * 4 + 1], vv[s4 * 4 + 2], vv[s4 * 4 + 3]};
      *(f16x4*)(Bs + col * PADK2 + kg * 16 + s4 * 4) = pk;
    }
  }
  __syncthreads();
  f32x4 acc[2][2] = {};
#pragma unroll
  for (int ks = 0; ks < 2; ++ks) {
    const int kofs = ks * 32 + ((lane >> 4) << 3);
    f16x8 a0 = *(const f16x8*)(As + (mh * 32 + 0  + (lane & 15)) * PADK2 + kofs);
    f16x8 a1 = *(const f16x8*)(As + (mh * 32 + 16 + (lane & 15)) * PADK2 + kofs);
    f16x8 b0 = *(const f16x8*)(Bs + (nh * 32 + 0  + (lane & 15)) * PADK2 + kofs);
    f16x8 b1 = *(const f16x8*)(Bs + (nh * 32 + 16 + (lane & 15)) * PADK2 + kofs);
    acc[0][0] = mfma16(a0, b0, acc[0][0]);
    acc[0][1] = mfma16(a0, b1, acc[0][1]);
    acc[1][0] = mfma16(a1, b0, acc[1][0]);
    acc[1][1] = mfma16(a1, b1, acc[1][1]);
  }
#pragma unroll
  for (int mf = 0; mf < 2; ++mf)
#pragma unroll
    for (int nf = 0; nf < 2; ++nf)
#pragma unroll
      for (int r = 0; r < 4; ++r) {
        int l = l0 + mh * 32 + mf * 16 + ((lane >> 4) << 2) + r;
        int col = n0 + nh * 32 + nf * 16 + (lane & 15);
        float cv = acc[mf][nf][r] * W1DESCALE + bo[col];
        out[((size_t)b * 2048 + l) * 512 + col] = cv;
      }
}

extern "C" void kernel_launch(void* const* d_in, const int* in_sizes, int n_in,
                              void* d_out, int out_size, void* d_ws, size_t ws_size,
                              hipStream_t stream) {
  const float* queries = (const float*)d_in[0];
  const float* Wq      = (const float*)d_in[1];
  const float* bq      = (const float*)d_in[2];
  const float* W1r     = (const float*)d_in[3];
  const float* W1i     = (const float*)d_in[4];
  const float* Wo      = (const float*)d_in[5];
  const float* bo      = (const float*)d_in[6];
  float* out           = (float*)d_out;

  char* ws = (char*)d_ws;
  size_t off = 0;
  auto alloc = [&](size_t bytes) {
    off = (off + 255) & ~(size_t)255;
    char* p = ws + off;
    off += bytes;
    return p;
  };
  f16* FhT    = (f16*)alloc((size_t)64 * 2048 * 2);
  f16* Gh     = (f16*)alloc((size_t)2048 * 64 * 2);
  f16* Wq16   = (f16*)alloc((size_t)512 * 512 * 2);
  f16* Wo16   = (f16*)alloc((size_t)512 * 512 * 2);
  f16* p16    = (f16*)alloc((size_t)4 * 2048 * 512 * 2);  // dft split-K f16 partials
  f16* selT   = (f16*)alloc((size_t)2048 * 512 * 2);      // [k2 plane][b][i]
  f16* pmode  = (f16*)alloc((size_t)4 * 2048 * 512 * 2);  // modes split f16 partials
  f16* u16    = (f16*)alloc((size_t)2048 * 512 * 2);

  hipLaunchKernelGGL(k_prep, dim3(512), dim3(256), 0, stream, FhT, Gh, Wq, Wo, Wq16, Wo16);
  hipLaunchKernelGGL(k_dft_fwd, dim3(8, 32, 4), dim3(256), 0, stream, FhT, queries, p16);
  hipLaunchKernelGGL(k_gemm_red<4>, dim3(16, 32), dim3(512), 0, stream, p16, Wq16, selT,
                     bq, 2048.0f, 1);
  hipLaunchKernelGGL(k_modes_fused, dim3(32, 2, 4), dim3(512), 0, stream,
                     W1r, W1i, selT, pmode);
  hipLaunchKernelGGL(k_gemm_red<4>, dim3(16, 32), dim3(512), 0, stream, pmode, Wo16, u16,
                     (const float*)nullptr, 0.0f, 0);
  hipLaunchKernelGGL(k_dft_inv, dim3(8, 32, 32), dim3(256), 0, stream, Gh, u16, bo, out);
}